// Round 8
// baseline (228.992 us; speedup 1.0000x reference)
//
#include <hip/hip_runtime.h>
#include <stdint.h>

// DeformableFusionAcrossFocus — round 13: r10 (VERIFIED transpose-free kernel)
// + r7 (VERIFIED XCD pair swizzle). One-line delta from a passed kernel.
// x:(2,64,16,96,96) f32 | w_off:(6,64,3) | b_off:(6) | w_def:(64,64,3) | b_def:(64) -> out f32
// Tile = (b,h,16w): pos = n*16+w in [0,256). Grid 1152 blocks x 512 thr, 1 tile each.
// r10's only regression vs r9 was traffic: WRITE 164MB (2.23x), FETCH 114MB (x+out/2)
// — unpaired 64B half-lines: consecutive blocks own the two halves of each 128B line
// but land on different XCDs (round-robin). r7's swizzle fixes exactly this:
// tn = (p&~15)|((p&7)<<1)|((p>>3)&1) pairs blocks p,p+8 (SAME XCD) onto adjacent
// wt tiles; every even-tn pair (tn,tn+1) shares bh and completes whole 128B lines
// for both x fetches and out writes in that XCD's L2. 1152%16==0 -> bijective.
// Staging: thread owns pos = t&255, channels cb..cb+31 (cb=(t>>8)*32); 32 scalar
// dword loads at c-stride (lanes 0-15 = 16 consecutive w = one 64B half-line, paired
// across the block pair). Data is c-contiguous -> 16 cvt_pk + 4 ds_write_b128 straight
// into xs_t[pos][c] — no xstage, no transpose, ONE barrier. 43008B LDS -> 3 blocks/CU.

typedef __attribute__((ext_vector_type(8))) short short8;
typedef __attribute__((ext_vector_type(4))) float f32x4;
typedef __attribute__((ext_vector_type(2))) float f32x2;
typedef __attribute__((ext_vector_type(4))) unsigned int u32x4;

// LDS (bytes):
//  [0,36864)      xs_t bf16 [pos][72 shorts] (row stride 144B; 64 c used + 8 pad)
//  [36864,43008)  offs f32 [6][256] (same-wave produce/consume)
#define XT_OFF   0
#define OFFS_OFF 36864
#define LDS_BYTES 43008   // 3 blocks/CU: 3*43008 = 129024 <= 163840

__device__ __forceinline__ short f2bf(float f) {
  union { float f; uint32_t u; } v; v.f = f;
  uint32_t r = (v.u + 0x7FFFu + ((v.u >> 16) & 1u)) >> 16;
  return (short)r;
}
__device__ __forceinline__ float asf(uint32_t u) {
  union { uint32_t u; float f; } v; v.u = u; return v.f;
}
__device__ __forceinline__ uint32_t cvt_pk_bf16(float lo, float hi) {
  uint32_t d;
  asm("v_cvt_pk_bf16_f32 %0, %1, %2" : "=v"(d) : "v"(lo), "v"(hi));
  return d;
}

// ---- prep: pre-swizzle w_def (frags [0,1536)) and w_off (frags [1536,1920)) into ws ----
__global__ __launch_bounds__(256) void prep_kernel(
    const float* __restrict__ w_off, const float* __restrict__ w_def, short8* __restrict__ ws)
{
  int gid = blockIdx.x * 256 + threadIdx.x;
  if (gid < 1536) {                      // q = (mt*6+ks)*64 + lane
    int mt = gid / 384, ks = (gid % 384) >> 6, ll = gid & 63;
    int m = mt * 16 + (ll & 15), rgq = ll >> 4;
    short8 v;
    #pragma unroll
    for (int jj = 0; jj < 8; ++jj) {
      int kk = ks * 32 + rgq * 8 + jj;
      int c = kk & 63, k3 = kk >> 6;
      v[jj] = f2bf(w_def[m * 192 + c * 3 + k3]);
    }
    ws[gid] = v;
  } else if (gid < 1920) {               // q = ks*64 + lane (rows 6..15 zero)
    int q = gid - 1536;
    int ks = q >> 6, ll = q & 63;
    int m = ll & 15, rgq = ll >> 4;
    short8 v;
    #pragma unroll
    for (int jj = 0; jj < 8; ++jj) {
      int kk = ks * 32 + rgq * 8 + jj;
      int c = kk & 63, k3 = kk >> 6;
      v[jj] = (m < 6) ? f2bf(w_off[m * 192 + c * 3 + k3]) : (short)0;
    }
    ws[gid] = v;
  }
}

__global__ __launch_bounds__(512, 6) void deform_main(
    const float* __restrict__ x, const float* __restrict__ b_off,
    const float* __restrict__ b_def, const short8* __restrict__ wfr,
    float* __restrict__ out)
{
  extern __shared__ char smem[];
  float* offs = (float*)(smem + OFFS_OFF);

  const int t = threadIdx.x, wv = t >> 6, l = t & 63, col = l & 15, rg = l >> 4;
  const int p = blockIdx.x;
  const int tn = (p & ~15) | ((p & 7) << 1) | ((p >> 3) & 1);   // r7 pair swizzle
  const int wt = tn % 6, bh = tn / 6;
  const int h = bh % 96, b = bh / 96, w0 = wt * 16;
  const float* xb = x + (size_t)b * 9437184 + h * 96 + w0;

  // ---- stage x -> xs_t[pos][c] directly (no xstage, no transpose) ----
  {
    int pos = t & 255, cb = (t >> 8) * 32;
    int n_ = pos >> 4, w_ = pos & 15;
    const float* xp = xb + (size_t)cb * 147456 + n_ * 9216 + w_;
    float vv[32];
    #pragma unroll
    for (int c = 0; c < 32; ++c)
      vv[c] = xp[(size_t)c * 147456];
    uint32_t pk[16];
    #pragma unroll
    for (int q = 0; q < 16; ++q) pk[q] = cvt_pk_bf16(vv[2 * q], vv[2 * q + 1]);
    #pragma unroll
    for (int q = 0; q < 4; ++q) {
      u32x4 wvec = { pk[4 * q], pk[4 * q + 1], pk[4 * q + 2], pk[4 * q + 3] };
      *(u32x4*)(smem + XT_OFF + pos * 144 + cb * 2 + q * 16) = wvec;
    }
  }
  __syncthreads();   // the ONLY barrier: xs_t complete

  // ---- offsets conv via MFMA; offs produced & consumed by the SAME wave ----
  {
    f32x4 cacc[2] = {{0.f,0.f,0.f,0.f},{0.f,0.f,0.f,0.f}};
    const short8 zero = {0,0,0,0,0,0,0,0};
    #pragma unroll
    for (int ks = 0; ks < 6; ++ks) {
      short8 av = wfr[1536 + ks * 64 + l];
      int k3 = ks >> 1;
      #pragma unroll
      for (int nt2 = 0; nt2 < 2; ++nt2) {
        int n = wv * 2 + nt2;              // pos = n*16 + col
        int row = n + k3 - 1;
        bool valid = (row >= 0) && (row < 16);
        int rcl = min(max(row, 0), 15);
        short8 bv = *(short8*)(smem + XT_OFF + (rcl * 16 + col) * 144 + rg * 16 + (ks & 1) * 64);
        bv = valid ? bv : zero;
        cacc[nt2] = __builtin_amdgcn_mfma_f32_16x16x32_bf16(av, bv, cacc[nt2], 0, 0, 0);
      }
    }
    #pragma unroll
    for (int nt2 = 0; nt2 < 2; ++nt2) {
      int pos = (wv * 2 + nt2) * 16 + col;
      #pragma unroll
      for (int r = 0; r < 4; ++r) {
        int rowo = rg * 4 + r;
        if (rowo < 6) offs[rowo * 256 + pos] = cacc[nt2][r];
      }
    }
  }
  // no barrier: same-wave LDS ordering suffices (offs pos ranges are per-wave)

  // ---- interp params, per-lane in registers (all loop indices constant) ----
  float a0v[3][2], a1v[3][2]; int rb[3][2];
  #pragma unroll
  for (int k = 0; k < 3; ++k) {
    #pragma unroll
    for (int nt2 = 0; nt2 < 2; ++nt2) {
      int n = wv * 2 + nt2;
      int pos = n * 16 + col;
      float oy = offs[(2 * k) * 256 + pos] + b_off[2 * k];
      float ox = offs[(2 * k + 1) * 256 + pos] + b_off[2 * k + 1];
      float px = (float)(n - 1 + k) + ox;
      float x0f = floorf(px);
      float fx = px - x0f;
      int x0 = (int)x0f;
      float wy = fmaxf(0.f, 1.f - fabsf(oy));
      float wt1v = fx * wy;
      float wt0v = wy - wt1v;
      float a0, a1; int r0;
      if (x0 >= 0 && x0 < 15)  { r0 = x0; a0 = wt0v; a1 = wt1v; }
      else if (x0 == 15)       { r0 = 14; a0 = 0.f;  a1 = wt0v; }  // only row 15 (=x0)
      else if (x0 == -1)       { r0 = 0;  a0 = wt1v; a1 = 0.f;  }  // only row 0 (=x1)
      else                     { r0 = 0;  a0 = 0.f;  a1 = 0.f;  }
      a0v[k][nt2] = a0; a1v[k][nt2] = a1;
      rb[k][nt2] = (r0 * 16 + col) * 144;
    }
  }

  // ---- main GEMM: 64 o x 32 pos per wave, K=192; fully unrolled ----
  f32x4 acc[4][2];
  #pragma unroll
  for (int mt = 0; mt < 4; ++mt) {
    float4 bd = *(const float4*)(b_def + mt * 16 + rg * 4);
    #pragma unroll
    for (int nt2 = 0; nt2 < 2; ++nt2) {
      acc[mt][nt2][0] = bd.x; acc[mt][nt2][1] = bd.y;
      acc[mt][nt2][2] = bd.z; acc[mt][nt2][3] = bd.w;
    }
  }
  #pragma unroll
  for (int k3 = 0; k3 < 3; ++k3) {
    #pragma unroll
    for (int ks2 = 0; ks2 < 2; ++ks2) {
      int ks = k3 * 2 + ks2;
      short8 A[4];
      #pragma unroll
      for (int mt = 0; mt < 4; ++mt) A[mt] = wfr[(mt * 6 + ks) * 64 + l];
      #pragma unroll
      for (int nt2 = 0; nt2 < 2; ++nt2) {
        const char* base = smem + XT_OFF + rb[k3][nt2] + rg * 16 + ks2 * 64;
        u32x4 x0 = *(const u32x4*)base;
        u32x4 x1 = *(const u32x4*)(base + 2304);   // tap row r0+1 (16 pos x stride 144)
        f32x2 A0 = {a0v[k3][nt2], a0v[k3][nt2]};
        f32x2 A1 = {a1v[k3][nt2], a1v[k3][nt2]};
        union { uint32_t w[4]; short8 s; } bu;
        #pragma unroll
        for (int q = 0; q < 4; ++q) {
          uint32_t u0 = x0[q], u1 = x1[q];
          f32x2 X0 = { asf(u0 << 16), asf(u0 & 0xffff0000u) };
          f32x2 X1 = { asf(u1 << 16), asf(u1 & 0xffff0000u) };
          f32x2 R = A0 * X0 + A1 * X1;
          bu.w[q] = cvt_pk_bf16(R.x, R.y);
        }
        short8 bv = bu.s;
        #pragma unroll
        for (int mt = 0; mt < 4; ++mt)
          acc[mt][nt2] = __builtin_amdgcn_mfma_f32_16x16x32_bf16(A[mt], bv, acc[mt][nt2], 0, 0, 0);
      }
    }
  }

  // ---- epilogue: direct stores; each 16-lane group writes one full 64B half-line,
  //      paired with block p^8's adjacent half in the same XCD's L2 ----
  float* ob = out + (size_t)b * 9437184 + h * 96 + w0;
  #pragma unroll
  for (int mt = 0; mt < 4; ++mt) {
    #pragma unroll
    for (int nt2 = 0; nt2 < 2; ++nt2) {
      int n = wv * 2 + nt2;
      float* o0 = ob + (size_t)((mt * 16 + rg * 4) * 16 + n) * 9216 + col;
      #pragma unroll
      for (int r = 0; r < 4; ++r)
        o0[(size_t)r * 147456] = acc[mt][nt2][r];   // o stride = 16*9216
    }
  }
}

extern "C" void kernel_launch(void* const* d_in, const int* in_sizes, int n_in,
                              void* d_out, int out_size, void* d_ws, size_t ws_size,
                              hipStream_t stream) {
  (void)in_sizes; (void)n_in; (void)ws_size; (void)out_size;
  const float* x     = (const float*)d_in[0];
  const float* w_off = (const float*)d_in[1];
  const float* b_off = (const float*)d_in[2];
  const float* w_def = (const float*)d_in[3];
  const float* b_def = (const float*)d_in[4];
  float* out = (float*)d_out;
  short8* wfr = (short8*)d_ws;   // 1920 * 16B = 30720 B of scratch

  (void)hipFuncSetAttribute((const void*)deform_main,
                            hipFuncAttributeMaxDynamicSharedMemorySize, LDS_BYTES);
  prep_kernel<<<dim3(8), dim3(256), 0, stream>>>(w_off, w_def, wfr);
  deform_main<<<dim3(1152), dim3(512), LDS_BYTES, stream>>>(x, b_off, b_def, wfr, out);
}

// Round 10
// 167.214 us; speedup vs baseline: 1.3695x; 1.3695x over previous
//
#include <hip/hip_runtime.h>
#include <stdint.h>

// DeformableFusionAcrossFocus — round 15: r9 (best VERIFIED kernel, 72.8µs) +
// r7/r13-VERIFIED XCD pair swizzle. One-line delta between two PASSED kernels.
// x:(2,64,16,96,96) f32 | w_off:(6,64,3) | b_off:(6) | w_def:(64,64,3) | b_def:(64) -> out f32
// Tile = (b,h,16w): pos = n*16+w in [0,256). Grid 1152 blocks x 512 thr, 1 tile each.
// Session record: verified-component assemblies 4/4 PASS; on-paper restructures
// (r12 32-wide XOR, r14 two-tile pipeline) 2/2 silent-corruption. So: bank the
// verified best, add only the verified swizzle.
// Swizzle tn = (p&~15)|((p&7)<<1)|((p>>3)&1): blocks p,p+8 (same XCD under
// round-robin) own adjacent 16-wide tiles = the two 64B halves of every 128B
// x/out line -> half-line pairing happens in one XCD's L2 regardless of timing
// (r13 measured: fixes FETCH 114->77MB under 3-blk/CU adversity; r9 at 2-blk/CU
// was clean by scheduling luck — this makes it structural). 1152%16==0: bijective.
// Everything else r9-verbatim: float4 coalesced stage (each row = one full 64B
// line) -> bf16 pack -> LDS transpose -> MFMA offsets conv (same-wave offs
// overlay) -> interp -> fully-unrolled 64o x 32pos GEMM -> direct 64B-line stores.

typedef __attribute__((ext_vector_type(8))) short short8;
typedef __attribute__((ext_vector_type(4))) float f32x4;
typedef __attribute__((ext_vector_type(2))) float f32x2;
typedef __attribute__((ext_vector_type(4))) unsigned int u32x4;

// LDS (bytes):
//  [0,36864)      xs_t bf16 [pos][72 shorts] (row stride 144B; 64 c used + 8 pad)
//  [36864,69632)  xstage bf16 [c*256 + pos] (dead after transpose)
//  [36864,43008)  offs f32 [6][256] (overlays dead xstage; same-wave produce/consume)
#define XT_OFF   0
#define XG_OFF   36864
#define OFFS_OFF 36864
#define LDS_BYTES 69632   // 2 blocks/CU: 2*69632 = 139264 <= 163840

__device__ __forceinline__ short f2bf(float f) {
  union { float f; uint32_t u; } v; v.f = f;
  uint32_t r = (v.u + 0x7FFFu + ((v.u >> 16) & 1u)) >> 16;
  return (short)r;
}
__device__ __forceinline__ float asf(uint32_t u) {
  union { uint32_t u; float f; } v; v.u = u; return v.f;
}
__device__ __forceinline__ uint32_t cvt_pk_bf16(float lo, float hi) {
  uint32_t d;
  asm("v_cvt_pk_bf16_f32 %0, %1, %2" : "=v"(d) : "v"(lo), "v"(hi));
  return d;
}

// ---- prep: pre-swizzle w_def (frags [0,1536)) and w_off (frags [1536,1920)) into ws ----
__global__ __launch_bounds__(256) void prep_kernel(
    const float* __restrict__ w_off, const float* __restrict__ w_def, short8* __restrict__ ws)
{
  int gid = blockIdx.x * 256 + threadIdx.x;
  if (gid < 1536) {                      // q = (mt*6+ks)*64 + lane
    int mt = gid / 384, ks = (gid % 384) >> 6, ll = gid & 63;
    int m = mt * 16 + (ll & 15), rgq = ll >> 4;
    short8 v;
    #pragma unroll
    for (int jj = 0; jj < 8; ++jj) {
      int kk = ks * 32 + rgq * 8 + jj;
      int c = kk & 63, k3 = kk >> 6;
      v[jj] = f2bf(w_def[m * 192 + c * 3 + k3]);
    }
    ws[gid] = v;
  } else if (gid < 1920) {               // q = ks*64 + lane (rows 6..15 zero)
    int q = gid - 1536;
    int ks = q >> 6, ll = q & 63;
    int m = ll & 15, rgq = ll >> 4;
    short8 v;
    #pragma unroll
    for (int jj = 0; jj < 8; ++jj) {
      int kk = ks * 32 + rgq * 8 + jj;
      int c = kk & 63, k3 = kk >> 6;
      v[jj] = (m < 6) ? f2bf(w_off[m * 192 + c * 3 + k3]) : (short)0;
    }
    ws[gid] = v;
  }
}

__global__ __launch_bounds__(512, 4) void deform_main(
    const float* __restrict__ x, const float* __restrict__ b_off,
    const float* __restrict__ b_def, const short8* __restrict__ wfr,
    float* __restrict__ out)
{
  extern __shared__ char smem[];
  uint16_t* xst = (uint16_t*)(smem + XG_OFF);
  float* offs   = (float*)(smem + OFFS_OFF);

  const int t = threadIdx.x, wv = t >> 6, l = t & 63, col = l & 15, rg = l >> 4;
  const int p = blockIdx.x;
  const int tn = (p & ~15) | ((p & 7) << 1) | ((p >> 3) & 1);   // r7/r13 pair swizzle
  const int wt = tn % 6, bh = tn / 6;
  const int h = bh % 96, b = bh / 96, w0 = wt * 16;
  const float* xb = x + (size_t)b * 9437184 + h * 96 + w0;

  // ---- stage x -> bf16 xstage [c][pos]; each row read = one full 64B line ----
  #pragma unroll
  for (int i = 0; i < 8; ++i) {
    int r = (t >> 2) + i * 128, quad = t & 3;       // r = c*16+n, 4 lanes per 64B row
    float4 v = *(const float4*)(xb + (size_t)r * 9216 + quad * 4);
    uint2 pk;
    pk.x = cvt_pk_bf16(v.x, v.y);
    pk.y = cvt_pk_bf16(v.z, v.w);
    *(uint2*)(xst + r * 16 + quad * 4) = pk;        // xstage idx = c*256 + n*16 + quad*4
  }
  __syncthreads();

  // ---- transpose -> xs_t[pos][c] (b128 writes; stride 144B) ----
  #pragma unroll
  for (int i = 0; i < 4; ++i) {
    int item = t + 512 * i;                // 2048 = 256 pos x 8 cgroups
    int pos = item & 255, cg = item >> 8;
    short8 vv;
    #pragma unroll
    for (int jj = 0; jj < 8; ++jj) vv[jj] = (short)xst[(cg * 8 + jj) * 256 + pos];
    *(short8*)(smem + XT_OFF + pos * 144 + cg * 16) = vv;
  }
  __syncthreads();   // xs_t complete; xstage dead (offs overlays it)

  // ---- offsets conv via MFMA; offs produced & consumed by the SAME wave ----
  {
    f32x4 cacc[2] = {{0.f,0.f,0.f,0.f},{0.f,0.f,0.f,0.f}};
    const short8 zero = {0,0,0,0,0,0,0,0};
    #pragma unroll
    for (int ks = 0; ks < 6; ++ks) {
      short8 av = wfr[1536 + ks * 64 + l];
      int k3 = ks >> 1;
      #pragma unroll
      for (int nt2 = 0; nt2 < 2; ++nt2) {
        int n = wv * 2 + nt2;              // pos = n*16 + col
        int row = n + k3 - 1;
        bool valid = (row >= 0) && (row < 16);
        int rcl = min(max(row, 0), 15);
        short8 bv = *(short8*)(smem + XT_OFF + (rcl * 16 + col) * 144 + rg * 16 + (ks & 1) * 64);
        bv = valid ? bv : zero;
        cacc[nt2] = __builtin_amdgcn_mfma_f32_16x16x32_bf16(av, bv, cacc[nt2], 0, 0, 0);
      }
    }
    #pragma unroll
    for (int nt2 = 0; nt2 < 2; ++nt2) {
      int pos = (wv * 2 + nt2) * 16 + col;
      #pragma unroll
      for (int r = 0; r < 4; ++r) {
        int rowo = rg * 4 + r;
        if (rowo < 6) offs[rowo * 256 + pos] = cacc[nt2][r];
      }
    }
  }
  // no barrier: same-wave LDS ordering suffices (offs pos ranges are per-wave)

  // ---- interp params, per-lane in registers (all loop indices constant) ----
  float a0v[3][2], a1v[3][2]; int rb[3][2];
  #pragma unroll
  for (int k = 0; k < 3; ++k) {
    #pragma unroll
    for (int nt2 = 0; nt2 < 2; ++nt2) {
      int n = wv * 2 + nt2;
      int pos = n * 16 + col;
      float oy = offs[(2 * k) * 256 + pos] + b_off[2 * k];
      float ox = offs[(2 * k + 1) * 256 + pos] + b_off[2 * k + 1];
      float px = (float)(n - 1 + k) + ox;
      float x0f = floorf(px);
      float fx = px - x0f;
      int x0 = (int)x0f;
      float wy = fmaxf(0.f, 1.f - fabsf(oy));
      float wt1v = fx * wy;
      float wt0v = wy - wt1v;
      float a0, a1; int r0;
      if (x0 >= 0 && x0 < 15)  { r0 = x0; a0 = wt0v; a1 = wt1v; }
      else if (x0 == 15)       { r0 = 14; a0 = 0.f;  a1 = wt0v; }  // only row 15 (=x0)
      else if (x0 == -1)       { r0 = 0;  a0 = wt1v; a1 = 0.f;  }  // only row 0 (=x1)
      else                     { r0 = 0;  a0 = 0.f;  a1 = 0.f;  }
      a0v[k][nt2] = a0; a1v[k][nt2] = a1;
      rb[k][nt2] = (r0 * 16 + col) * 144;
    }
  }

  // ---- main GEMM: 64 o x 32 pos per wave, K=192; fully unrolled ----
  f32x4 acc[4][2];
  #pragma unroll
  for (int mt = 0; mt < 4; ++mt) {
    float4 bd = *(const float4*)(b_def + mt * 16 + rg * 4);
    #pragma unroll
    for (int nt2 = 0; nt2 < 2; ++nt2) {
      acc[mt][nt2][0] = bd.x; acc[mt][nt2][1] = bd.y;
      acc[mt][nt2][2] = bd.z; acc[mt][nt2][3] = bd.w;
    }
  }
  #pragma unroll
  for (int k3 = 0; k3 < 3; ++k3) {
    #pragma unroll
    for (int ks2 = 0; ks2 < 2; ++ks2) {
      int ks = k3 * 2 + ks2;
      short8 A[4];
      #pragma unroll
      for (int mt = 0; mt < 4; ++mt) A[mt] = wfr[(mt * 6 + ks) * 64 + l];
      #pragma unroll
      for (int nt2 = 0; nt2 < 2; ++nt2) {
        const char* base = smem + XT_OFF + rb[k3][nt2] + rg * 16 + ks2 * 64;
        u32x4 x0 = *(const u32x4*)base;
        u32x4 x1 = *(const u32x4*)(base + 2304);   // tap row r0+1 (16 pos x stride 144)
        f32x2 A0 = {a0v[k3][nt2], a0v[k3][nt2]};
        f32x2 A1 = {a1v[k3][nt2], a1v[k3][nt2]};
        union { uint32_t w[4]; short8 s; } bu;
        #pragma unroll
        for (int q = 0; q < 4; ++q) {
          uint32_t u0 = x0[q], u1 = x1[q];
          f32x2 X0 = { asf(u0 << 16), asf(u0 & 0xffff0000u) };
          f32x2 X1 = { asf(u1 << 16), asf(u1 & 0xffff0000u) };
          f32x2 R = A0 * X0 + A1 * X1;
          bu.w[q] = cvt_pk_bf16(R.x, R.y);
        }
        short8 bv = bu.s;
        #pragma unroll
        for (int mt = 0; mt < 4; ++mt)
          acc[mt][nt2] = __builtin_amdgcn_mfma_f32_16x16x32_bf16(A[mt], bv, acc[mt][nt2], 0, 0, 0);
      }
    }
  }

  // ---- epilogue: direct stores; each 16-lane group writes one full 64B line,
  //      paired with block p^8's adjacent half in the same XCD's L2 ----
  float* ob = out + (size_t)b * 9437184 + h * 96 + w0;
  #pragma unroll
  for (int mt = 0; mt < 4; ++mt) {
    #pragma unroll
    for (int nt2 = 0; nt2 < 2; ++nt2) {
      int n = wv * 2 + nt2;
      float* o0 = ob + (size_t)((mt * 16 + rg * 4) * 16 + n) * 9216 + col;
      #pragma unroll
      for (int r = 0; r < 4; ++r)
        o0[(size_t)r * 147456] = acc[mt][nt2][r];   // o stride = 16*9216
    }
  }
}

extern "C" void kernel_launch(void* const* d_in, const int* in_sizes, int n_in,
                              void* d_out, int out_size, void* d_ws, size_t ws_size,
                              hipStream_t stream) {
  (void)in_sizes; (void)n_in; (void)ws_size; (void)out_size;
  const float* x     = (const float*)d_in[0];
  const float* w_off = (const float*)d_in[1];
  const float* b_off = (const float*)d_in[2];
  const float* w_def = (const float*)d_in[3];
  const float* b_def = (const float*)d_in[4];
  float* out = (float*)d_out;
  short8* wfr = (short8*)d_ws;   // 1920 * 16B = 30720 B of scratch

  (void)hipFuncSetAttribute((const void*)deform_main,
                            hipFuncAttributeMaxDynamicSharedMemorySize, LDS_BYTES);
  prep_kernel<<<dim3(8), dim3(256), 0, stream>>>(w_off, w_def, wfr);
  deform_main<<<dim3(1152), dim3(512), LDS_BYTES, stream>>>(x, b_off, b_def, wfr, out);
}